// Round 1
// baseline (640.778 us; speedup 1.0000x reference)
//
#include <hip/hip_runtime.h>

typedef __bf16 bf16x4 __attribute__((ext_vector_type(4)));
typedef __bf16 bf16x8 __attribute__((ext_vector_type(8)));
typedef float  f32x4  __attribute__((ext_vector_type(4)));

#define TILE_M 128
#define TILE_N 128
#define TILE_K 32
#define LDSS   40   // padded LDS row stride in bf16 elems (80 B, 16B-aligned, breaks pow2 bank stride)

// ---------------------------------------------------------------------------
// GEMM: C[m][n] = sum_k A[m][k] * W[n][k]   (A:[M,K] fp32, W:[N,K] fp32)
// bf16 MFMA 16x16x32, 128x128 tile, BK=32, in-kernel fp32->bf16 convert.
// ---------------------------------------------------------------------------
__global__ __launch_bounds__(256) void gemm_kernel(
    const float* __restrict__ A, const float* __restrict__ W,
    float* __restrict__ C, int M, int N, int K)
{
    __shared__ __align__(16) __bf16 As[TILE_M * LDSS];
    __shared__ __align__(16) __bf16 Bs[TILE_N * LDSS];

    const int tid  = threadIdx.x;
    const int lane = tid & 63;
    const int wave = tid >> 6;
    const int wm   = wave >> 1;        // wave row (0..1) -> 64 rows
    const int wn   = wave & 1;         // wave col (0..1) -> 64 cols
    const int quad = lane >> 4;        // 0..3
    const int l16  = lane & 15;

    const int row0 = blockIdx.y * TILE_M;
    const int col0 = blockIdx.x * TILE_N;

    f32x4 acc[4][4];
#pragma unroll
    for (int i = 0; i < 4; ++i)
#pragma unroll
        for (int j = 0; j < 4; ++j) {
            f32x4 z = {0.f, 0.f, 0.f, 0.f};
            acc[i][j] = z;
        }

    for (int k0 = 0; k0 < K; k0 += TILE_K) {
        __syncthreads();   // protect LDS from previous iteration's readers
        // stage 128x32 fp32 -> bf16 for A and W; 1024 float4 chunks each, 4/thread
#pragma unroll
        for (int i = 0; i < 4; ++i) {
            int chunk = tid + i * 256;
            int r  = chunk >> 3;      // 0..127
            int c4 = chunk & 7;       // 0..7 (float4 index within 32-wide k)
            float4 av = *(const float4*)&A[(size_t)(row0 + r) * K + k0 + c4 * 4];
            float4 bv = *(const float4*)&W[(size_t)(col0 + r) * K + k0 + c4 * 4];
            bf16x4 a16 = { (__bf16)av.x, (__bf16)av.y, (__bf16)av.z, (__bf16)av.w };
            bf16x4 b16 = { (__bf16)bv.x, (__bf16)bv.y, (__bf16)bv.z, (__bf16)bv.w };
            *(bf16x4*)&As[r * LDSS + c4 * 4] = a16;
            *(bf16x4*)&Bs[r * LDSS + c4 * 4] = b16;
        }
        __syncthreads();

        bf16x8 af[4], bfv[4];
#pragma unroll
        for (int i = 0; i < 4; ++i)
            af[i]  = *(const bf16x8*)&As[(wm * 64 + i * 16 + l16) * LDSS + quad * 8];
#pragma unroll
        for (int j = 0; j < 4; ++j)
            bfv[j] = *(const bf16x8*)&Bs[(wn * 64 + j * 16 + l16) * LDSS + quad * 8];

#pragma unroll
        for (int i = 0; i < 4; ++i)
#pragma unroll
            for (int j = 0; j < 4; ++j)
                acc[i][j] = __builtin_amdgcn_mfma_f32_16x16x32_bf16(af[i], bfv[j], acc[i][j], 0, 0, 0);
    }

    // epilogue: C/D layout col = lane&15, row = quad*4 + reg
#pragma unroll
    for (int i = 0; i < 4; ++i)
#pragma unroll
        for (int j = 0; j < 4; ++j)
#pragma unroll
            for (int r = 0; r < 4; ++r) {
                int rr = row0 + wm * 64 + i * 16 + quad * 4 + r;
                int cc = col0 + wn * 64 + j * 16 + l16;
                C[(size_t)rr * N + cc] = acc[i][j][r];
            }
}

// ---------------------------------------------------------------------------
// Ghost-BN stats: per (group g of 128 rows, column) mean and rsqrt(var+eps)
// ---------------------------------------------------------------------------
__global__ __launch_bounds__(256) void stats_kernel(
    const float* __restrict__ x, float* __restrict__ mean_o,
    float* __restrict__ rstd_o, int N)
{
    int col = blockIdx.x * 256 + threadIdx.x;
    int g   = blockIdx.y;
    const float* p = x + (size_t)g * 128 * N + col;
    float s = 0.f, ss = 0.f;
#pragma unroll 4
    for (int r = 0; r < 128; ++r) {
        float v = p[(size_t)r * N];
        s += v; ss += v * v;
    }
    float m   = s * (1.f / 128.f);
    float var = ss * (1.f / 128.f) - m * m;
    mean_o[(size_t)g * N + col] = m;
    rstd_o[(size_t)g * N + col] = rsqrtf(var + 1e-5f);
}

// ---------------------------------------------------------------------------
// BN apply * priors -> sparsemax (Michelot exact projection), 1 wave / row
// ---------------------------------------------------------------------------
__device__ inline float waveReduceSum(float v) {
#pragma unroll
    for (int m = 1; m < 64; m <<= 1) v += __shfl_xor(v, m, 64);
    return v;
}
__device__ inline float waveReduceMax(float v) {
#pragma unroll
    for (int m = 1; m < 64; m <<= 1) v = fmaxf(v, __shfl_xor(v, m, 64));
    return v;
}

__global__ __launch_bounds__(256) void bn_sparsemax_kernel(
    float* __restrict__ x,                // in: GEMM out; out: final (in-place)
    const float* __restrict__ priors,
    const float* __restrict__ gamma,
    const float* __restrict__ beta,
    const float* __restrict__ mean_s,
    const float* __restrict__ rstd_s,
    int N)
{
    const int lane = threadIdx.x & 63;
    const int rib  = threadIdx.x >> 6;
    const int row  = blockIdx.x * 4 + rib;
    const int g    = row >> 7;            // VBS = 128
    const size_t base = (size_t)row * N;

    float z[32];
#pragma unroll
    for (int j = 0; j < 8; ++j) {
        int c = j * 256 + lane * 4;
        float4 xv = *(const float4*)&x[base + c];
        float4 pv = *(const float4*)&priors[base + c];
        float4 gv = *(const float4*)&gamma[c];
        float4 bv = *(const float4*)&beta[c];
        float4 mv = *(const float4*)&mean_s[(size_t)g * N + c];
        float4 rv = *(const float4*)&rstd_s[(size_t)g * N + c];
        z[j * 4 + 0] = ((xv.x - mv.x) * rv.x * gv.x + bv.x) * pv.x;
        z[j * 4 + 1] = ((xv.y - mv.y) * rv.y * gv.y + bv.y) * pv.y;
        z[j * 4 + 2] = ((xv.z - mv.z) * rv.z * gv.z + bv.z) * pv.z;
        z[j * 4 + 3] = ((xv.w - mv.w) * rv.w * gv.w + bv.w) * pv.w;
    }

    // Michelot: tau_{t+1} = (sum_{z>tau} z - 1) / |{z>tau}|, support shrinks, exact at FP
    float s0 = 0.f;
#pragma unroll
    for (int i = 0; i < 32; ++i) s0 += z[i];
    s0 = waveReduceSum(s0);
    float tau   = (s0 - 1.0f) / (float)N;
    float kprev = (float)N;
    for (int it = 0; it < 64; ++it) {
        float s = 0.f, c = 0.f;
#pragma unroll
        for (int i = 0; i < 32; ++i) {
            bool m = z[i] > tau;
            s += m ? z[i] : 0.f;
            c += m ? 1.f  : 0.f;
        }
        s = waveReduceSum(s);
        c = waveReduceSum(c);
        float tnew = (s - 1.0f) / c;
        bool done = (c == kprev);
        kprev = c;
        tau = tnew;
        if (done) break;   // support unchanged -> tau exact (wave-uniform branch)
    }

#pragma unroll
    for (int j = 0; j < 8; ++j) {
        int c = j * 256 + lane * 4;
        float4 o;
        o.x = fmaxf(z[j * 4 + 0] - tau, 0.f);
        o.y = fmaxf(z[j * 4 + 1] - tau, 0.f);
        o.z = fmaxf(z[j * 4 + 2] - tau, 0.f);
        o.w = fmaxf(z[j * 4 + 3] - tau, 0.f);
        *(float4*)&x[base + c] = o;
    }
}

// ---------------------------------------------------------------------------
extern "C" void kernel_launch(void* const* d_in, const int* in_sizes, int n_in,
                              void* d_out, int out_size, void* d_ws, size_t ws_size,
                              hipStream_t stream)
{
    const float* priors = (const float*)d_in[0];
    const float* feat   = (const float*)d_in[1];
    const float* fc_w   = (const float*)d_in[2];
    const float* gamma  = (const float*)d_in[3];
    const float* beta   = (const float*)d_in[4];
    float* out = (float*)d_out;

    const int G = in_sizes[3];               // 2048
    const int K = in_sizes[2] / G;           // 2048
    const int B = in_sizes[1] / K;           // 16384
    const int nGroups = B / 128;             // 128

    float* mean_s = (float*)d_ws;
    float* rstd_s = mean_s + (size_t)nGroups * G;

    // 1) GEMM -> d_out holds x = feat @ fc_w^T
    gemm_kernel<<<dim3(G / TILE_N, B / TILE_M), 256, 0, stream>>>(feat, fc_w, out, B, G, K);
    // 2) ghost-BN stats per (group, col)
    stats_kernel<<<dim3(G / 256, nGroups), 256, 0, stream>>>(out, mean_s, rstd_s, G);
    // 3) BN apply * priors -> sparsemax, in-place on d_out
    bn_sparsemax_kernel<<<B / 4, 256, 0, stream>>>(out, priors, gamma, beta, mean_s, rstd_s, G);
}

// Round 2
// 536.070 us; speedup vs baseline: 1.1953x; 1.1953x over previous
//
#include <hip/hip_runtime.h>

typedef __bf16 bf16x4 __attribute__((ext_vector_type(4)));
typedef __bf16 bf16x8 __attribute__((ext_vector_type(8)));
typedef float  f32x4  __attribute__((ext_vector_type(4)));

#define GLD16(gp, lp) __builtin_amdgcn_global_load_lds( \
    (const __attribute__((address_space(1))) void*)(gp), \
    (__attribute__((address_space(3))) void*)(lp), 16, 0, 0)

#define TILE_M 128
#define TILE_N 128
#define TILE_K 32

// ---------------------------------------------------------------------------
// fp32 -> bf16 one-shot convert (feat then fc_w, one grid)
// ---------------------------------------------------------------------------
__global__ __launch_bounds__(256) void convert_kernel(
    const float* __restrict__ feat, const float* __restrict__ w,
    __bf16* __restrict__ featb, __bf16* __restrict__ wb,
    long nFeat, long nW)
{
    long i = ((long)blockIdx.x * 256 + threadIdx.x) * 8;
    if (i < nFeat) {
        float4 a = *(const float4*)&feat[i];
        float4 b = *(const float4*)&feat[i + 4];
        bf16x8 o = {(__bf16)a.x,(__bf16)a.y,(__bf16)a.z,(__bf16)a.w,
                    (__bf16)b.x,(__bf16)b.y,(__bf16)b.z,(__bf16)b.w};
        *(bf16x8*)&featb[i] = o;
    } else {
        long j = i - nFeat;
        if (j < nW) {
            float4 a = *(const float4*)&w[j];
            float4 b = *(const float4*)&w[j + 4];
            bf16x8 o = {(__bf16)a.x,(__bf16)a.y,(__bf16)a.z,(__bf16)a.w,
                        (__bf16)b.x,(__bf16)b.y,(__bf16)b.z,(__bf16)b.w};
            *(bf16x8*)&wb[j] = o;
        }
    }
}

// ---------------------------------------------------------------------------
// Shared epilogue: write C tile + fused ghost-BN stats -> scale/shift
// (TILE_M == VBS == 128, so each block covers one full virtual batch slice)
// ---------------------------------------------------------------------------
__device__ __forceinline__ void epilogue_fused_stats(
    f32x4 (&acc)[4][4], float* __restrict__ C,
    float* __restrict__ scale_o, float* __restrict__ shift_o,
    const float* __restrict__ gamma, const float* __restrict__ beta,
    float (*sred)[2][128],
    int row0, int col0, int N, int wm, int wn, int quad, int l16, int tid)
{
    float psum[4] = {0,0,0,0}, pssq[4] = {0,0,0,0};
#pragma unroll
    for (int i = 0; i < 4; ++i)
#pragma unroll
        for (int j = 0; j < 4; ++j)
#pragma unroll
            for (int r = 0; r < 4; ++r) {
                float v = acc[i][j][r];
                int rr = row0 + wm * 64 + i * 16 + quad * 4 + r;
                int cc = col0 + wn * 64 + j * 16 + l16;
                C[(size_t)rr * N + cc] = v;
                psum[j] += v;
                pssq[j] += v * v;
            }
    // reduce across quad (rows) within the wave
#pragma unroll
    for (int j = 0; j < 4; ++j) {
        psum[j] += __shfl_xor(psum[j], 16, 64);
        psum[j] += __shfl_xor(psum[j], 32, 64);
        pssq[j] += __shfl_xor(pssq[j], 16, 64);
        pssq[j] += __shfl_xor(pssq[j], 32, 64);
    }
    if (quad == 0) {
#pragma unroll
        for (int j = 0; j < 4; ++j) {
            int ccL = wn * 64 + j * 16 + l16;
            sred[wm][0][ccL] = psum[j];
            sred[wm][1][ccL] = pssq[j];
        }
    }
    __syncthreads();
    if (tid < 128) {
        float s  = sred[0][0][tid] + sred[1][0][tid];
        float ss = sred[0][1][tid] + sred[1][1][tid];
        float m  = s * (1.f / 128.f);
        float var = ss * (1.f / 128.f) - m * m;
        float rstd = rsqrtf(var + 1e-5f);
        int g = row0 >> 7;
        int col = col0 + tid;
        float a = rstd * gamma[col];
        float b = beta[col] - m * a;
        scale_o[(size_t)g * N + col] = a;
        shift_o[(size_t)g * N + col] = b;
    }
}

// ---------------------------------------------------------------------------
// Fast GEMM: bf16 inputs, m97 structure (global_load_lds width=16, unpadded
// 64B LDS rows), fused stats epilogue.  C = A @ W^T
// ---------------------------------------------------------------------------
__global__ __launch_bounds__(256) void gemm_bf16_kernel(
    const __bf16* __restrict__ A, const __bf16* __restrict__ W,
    float* __restrict__ C, float* __restrict__ scale_o, float* __restrict__ shift_o,
    const float* __restrict__ gamma, const float* __restrict__ beta,
    int M, int N, int K)
{
    __shared__ __align__(16) __bf16 As[TILE_M * TILE_K];   // 64B rows, NO pad (global_load_lds)
    __shared__ __align__(16) __bf16 Bs[TILE_N * TILE_K];
    __shared__ float sred[2][2][128];

    const int tid  = threadIdx.x;
    const int lane = tid & 63;
    const int wave = tid >> 6;
    const int wm   = wave >> 1;
    const int wn   = wave & 1;
    const int quad = lane >> 4;
    const int l16  = lane & 15;

    const int row0 = blockIdx.y * TILE_M;
    const int col0 = blockIdx.x * TILE_N;

    const int srow = lane >> 2;          // 0..15: row within 16-row chunk
    const int skof = (lane & 3) * 8;     // bf16 elems within 32-wide k

    f32x4 acc[4][4];
#pragma unroll
    for (int i = 0; i < 4; ++i)
#pragma unroll
        for (int j = 0; j < 4; ++j) {
            f32x4 z = {0.f, 0.f, 0.f, 0.f};
            acc[i][j] = z;
        }

    for (int k0 = 0; k0 < K; k0 += TILE_K) {
        __syncthreads();
        // wave w stages A rows [w*32, w*32+32) and B rows likewise; 16 rows (1KB) per inst
#pragma unroll
        for (int c = 0; c < 2; ++c) {
            int rbase = wave * 32 + c * 16;
            const __bf16* ga = &A[(size_t)(row0 + rbase + srow) * K + k0 + skof];
            const __bf16* gb = &W[(size_t)(col0 + rbase + srow) * K + k0 + skof];
            GLD16(ga, &As[rbase * TILE_K]);
            GLD16(gb, &Bs[rbase * TILE_K]);
        }
        __syncthreads();

        bf16x8 af[4], bfv[4];
#pragma unroll
        for (int i = 0; i < 4; ++i)
            af[i]  = *(const bf16x8*)&As[(wm * 64 + i * 16 + l16) * TILE_K + quad * 8];
#pragma unroll
        for (int j = 0; j < 4; ++j)
            bfv[j] = *(const bf16x8*)&Bs[(wn * 64 + j * 16 + l16) * TILE_K + quad * 8];

#pragma unroll
        for (int i = 0; i < 4; ++i)
#pragma unroll
            for (int j = 0; j < 4; ++j)
                acc[i][j] = __builtin_amdgcn_mfma_f32_16x16x32_bf16(af[i], bfv[j], acc[i][j], 0, 0, 0);
    }

    epilogue_fused_stats(acc, C, scale_o, shift_o, gamma, beta, sred,
                         row0, col0, N, wm, wn, quad, l16, tid);
}

// ---------------------------------------------------------------------------
// Fallback GEMM (ws too small for bf16 copies): fp32 inputs, in-kernel convert
// ---------------------------------------------------------------------------
#define LDSS 40
__global__ __launch_bounds__(256) void gemm_f32_kernel(
    const float* __restrict__ A, const float* __restrict__ W,
    float* __restrict__ C, float* __restrict__ scale_o, float* __restrict__ shift_o,
    const float* __restrict__ gamma, const float* __restrict__ beta,
    int M, int N, int K)
{
    __shared__ __align__(16) __bf16 As[TILE_M * LDSS];
    __shared__ __align__(16) __bf16 Bs[TILE_N * LDSS];
    __shared__ float sred[2][2][128];

    const int tid  = threadIdx.x;
    const int lane = tid & 63;
    const int wave = tid >> 6;
    const int wm   = wave >> 1;
    const int wn   = wave & 1;
    const int quad = lane >> 4;
    const int l16  = lane & 15;

    const int row0 = blockIdx.y * TILE_M;
    const int col0 = blockIdx.x * TILE_N;

    f32x4 acc[4][4];
#pragma unroll
    for (int i = 0; i < 4; ++i)
#pragma unroll
        for (int j = 0; j < 4; ++j) {
            f32x4 z = {0.f, 0.f, 0.f, 0.f};
            acc[i][j] = z;
        }

    for (int k0 = 0; k0 < K; k0 += TILE_K) {
        __syncthreads();
#pragma unroll
        for (int i = 0; i < 4; ++i) {
            int chunk = tid + i * 256;
            int r  = chunk >> 3;
            int c4 = chunk & 7;
            float4 av = *(const float4*)&A[(size_t)(row0 + r) * K + k0 + c4 * 4];
            float4 bv = *(const float4*)&W[(size_t)(col0 + r) * K + k0 + c4 * 4];
            bf16x4 a16 = { (__bf16)av.x, (__bf16)av.y, (__bf16)av.z, (__bf16)av.w };
            bf16x4 b16 = { (__bf16)bv.x, (__bf16)bv.y, (__bf16)bv.z, (__bf16)bv.w };
            *(bf16x4*)&As[r * LDSS + c4 * 4] = a16;
            *(bf16x4*)&Bs[r * LDSS + c4 * 4] = b16;
        }
        __syncthreads();

        bf16x8 af[4], bfv[4];
#pragma unroll
        for (int i = 0; i < 4; ++i)
            af[i]  = *(const bf16x8*)&As[(wm * 64 + i * 16 + l16) * LDSS + quad * 8];
#pragma unroll
        for (int j = 0; j < 4; ++j)
            bfv[j] = *(const bf16x8*)&Bs[(wn * 64 + j * 16 + l16) * LDSS + quad * 8];

#pragma unroll
        for (int i = 0; i < 4; ++i)
#pragma unroll
            for (int j = 0; j < 4; ++j)
                acc[i][j] = __builtin_amdgcn_mfma_f32_16x16x32_bf16(af[i], bfv[j], acc[i][j], 0, 0, 0);
    }

    epilogue_fused_stats(acc, C, scale_o, shift_o, gamma, beta, sred,
                         row0, col0, N, wm, wn, quad, l16, tid);
}

// ---------------------------------------------------------------------------
// BN-apply (pre-folded scale/shift) * priors -> sparsemax (Michelot), 1 wave/row
// ---------------------------------------------------------------------------
__device__ __forceinline__ float waveReduceSum(float v) {
#pragma unroll
    for (int m = 1; m < 64; m <<= 1) v += __shfl_xor(v, m, 64);
    return v;
}

__global__ __launch_bounds__(256) void bn_sparsemax_kernel(
    float* __restrict__ x,                // in: GEMM out; out: final (in-place)
    const float* __restrict__ priors,
    const float* __restrict__ scale_s,
    const float* __restrict__ shift_s,
    int N)
{
    const int lane = threadIdx.x & 63;
    const int rib  = threadIdx.x >> 6;
    const int row  = blockIdx.x * 4 + rib;
    const int g    = row >> 7;            // VBS = 128
    const size_t base = (size_t)row * N;

    float z[32];
#pragma unroll
    for (int j = 0; j < 8; ++j) {
        int c = j * 256 + lane * 4;
        float4 xv = *(const float4*)&x[base + c];
        float4 pv = *(const float4*)&priors[base + c];
        float4 av = *(const float4*)&scale_s[(size_t)g * N + c];
        float4 bv = *(const float4*)&shift_s[(size_t)g * N + c];
        z[j * 4 + 0] = fmaf(xv.x, av.x, bv.x) * pv.x;
        z[j * 4 + 1] = fmaf(xv.y, av.y, bv.y) * pv.y;
        z[j * 4 + 2] = fmaf(xv.z, av.z, bv.z) * pv.z;
        z[j * 4 + 3] = fmaf(xv.w, av.w, bv.w) * pv.w;
    }

    float s0 = 0.f;
#pragma unroll
    for (int i = 0; i < 32; ++i) s0 += z[i];
    s0 = waveReduceSum(s0);
    float tau   = (s0 - 1.0f) / (float)N;
    float kprev = (float)N;
    for (int it = 0; it < 64; ++it) {
        float s = 0.f, c = 0.f;
#pragma unroll
        for (int i = 0; i < 32; ++i) {
            bool m = z[i] > tau;
            s += m ? z[i] : 0.f;
            c += m ? 1.f  : 0.f;
        }
        s = waveReduceSum(s);
        c = waveReduceSum(c);
        float tnew = (s - 1.0f) / c;
        bool done = (c == kprev);
        kprev = c;
        tau = tnew;
        if (done) break;   // support unchanged -> tau exact (wave-uniform branch)
    }

#pragma unroll
    for (int j = 0; j < 8; ++j) {
        int c = j * 256 + lane * 4;
        float4 o;
        o.x = fmaxf(z[j * 4 + 0] - tau, 0.f);
        o.y = fmaxf(z[j * 4 + 1] - tau, 0.f);
        o.z = fmaxf(z[j * 4 + 2] - tau, 0.f);
        o.w = fmaxf(z[j * 4 + 3] - tau, 0.f);
        *(float4*)&x[base + c] = o;
    }
}

// ---------------------------------------------------------------------------
extern "C" void kernel_launch(void* const* d_in, const int* in_sizes, int n_in,
                              void* d_out, int out_size, void* d_ws, size_t ws_size,
                              hipStream_t stream)
{
    const float* priors = (const float*)d_in[0];
    const float* feat   = (const float*)d_in[1];
    const float* fc_w   = (const float*)d_in[2];
    const float* gamma  = (const float*)d_in[3];
    const float* beta   = (const float*)d_in[4];
    float* out = (float*)d_out;

    const int G = in_sizes[3];               // 2048
    const int K = in_sizes[2] / G;           // 2048
    const int B = in_sizes[1] / K;           // 16384
    const int nGroups = B / 128;             // 128

    const size_t statsElems = (size_t)nGroups * G;          // per array
    float* scale_s = (float*)d_ws;
    float* shift_s = scale_s + statsElems;
    char* wsAfterStats = (char*)(shift_s + statsElems);

    const size_t nFeat = (size_t)B * K;
    const size_t nW    = (size_t)G * K;
    const size_t needFast = 2 * statsElems * sizeof(float) + (nFeat + nW) * sizeof(__bf16);

    if (ws_size >= needFast) {
        __bf16* featb = (__bf16*)wsAfterStats;
        __bf16* wb    = featb + nFeat;
        long totalChunks = (long)((nFeat + nW) / 8);
        convert_kernel<<<(totalChunks + 255) / 256, 256, 0, stream>>>(
            feat, fc_w, featb, wb, (long)nFeat, (long)nW);
        gemm_bf16_kernel<<<dim3(G / TILE_N, B / TILE_M), 256, 0, stream>>>(
            featb, wb, out, scale_s, shift_s, gamma, beta, B, G, K);
    } else {
        gemm_f32_kernel<<<dim3(G / TILE_N, B / TILE_M), 256, 0, stream>>>(
            feat, fc_w, out, scale_s, shift_s, gamma, beta, B, G, K);
    }
    bn_sparsemax_kernel<<<B / 4, 256, 0, stream>>>(out, priors, scale_s, shift_s, G);
}

// Round 3
// 532.821 us; speedup vs baseline: 1.2026x; 1.0061x over previous
//
#include <hip/hip_runtime.h>

typedef __bf16 bf16x4 __attribute__((ext_vector_type(4)));
typedef __bf16 bf16x8 __attribute__((ext_vector_type(8)));
typedef float  f32x4  __attribute__((ext_vector_type(4)));

#define GLD16(gp, lp) __builtin_amdgcn_global_load_lds( \
    (const __attribute__((address_space(1))) void*)(gp), \
    (__attribute__((address_space(3))) void*)(lp), 16, 0, 0)

#define TILE_M 128
#define TILE_N 128
#define TILE_K 32

// ---------------------------------------------------------------------------
// fp32 -> bf16 one-shot convert (feat then fc_w, one grid)
// ---------------------------------------------------------------------------
__global__ __launch_bounds__(256) void convert_kernel(
    const float* __restrict__ feat, const float* __restrict__ w,
    __bf16* __restrict__ featb, __bf16* __restrict__ wb,
    long nFeat, long nW)
{
    long i = ((long)blockIdx.x * 256 + threadIdx.x) * 8;
    if (i < nFeat) {
        float4 a = *(const float4*)&feat[i];
        float4 b = *(const float4*)&feat[i + 4];
        bf16x8 o = {(__bf16)a.x,(__bf16)a.y,(__bf16)a.z,(__bf16)a.w,
                    (__bf16)b.x,(__bf16)b.y,(__bf16)b.z,(__bf16)b.w};
        *(bf16x8*)&featb[i] = o;
    } else {
        long j = i - nFeat;
        if (j < nW) {
            float4 a = *(const float4*)&w[j];
            float4 b = *(const float4*)&w[j + 4];
            bf16x8 o = {(__bf16)a.x,(__bf16)a.y,(__bf16)a.z,(__bf16)a.w,
                        (__bf16)b.x,(__bf16)b.y,(__bf16)b.z,(__bf16)b.w};
            *(bf16x8*)&wb[j] = o;
        }
    }
}

// ---------------------------------------------------------------------------
// Shared epilogue: write C tile + fused ghost-BN stats -> scale/shift
// (TILE_M == VBS == 128, so each block covers one full virtual batch slice)
// ---------------------------------------------------------------------------
__device__ __forceinline__ void epilogue_fused_stats(
    f32x4 (&acc)[4][4], float* __restrict__ C,
    float* __restrict__ scale_o, float* __restrict__ shift_o,
    const float* __restrict__ gamma, const float* __restrict__ beta,
    float (*sred)[2][128],
    int row0, int col0, int N, int wm, int wn, int quad, int l16, int tid)
{
    float psum[4] = {0,0,0,0}, pssq[4] = {0,0,0,0};
#pragma unroll
    for (int i = 0; i < 4; ++i)
#pragma unroll
        for (int j = 0; j < 4; ++j)
#pragma unroll
            for (int r = 0; r < 4; ++r) {
                float v = acc[i][j][r];
                int rr = row0 + wm * 64 + i * 16 + quad * 4 + r;
                int cc = col0 + wn * 64 + j * 16 + l16;
                C[(size_t)rr * N + cc] = v;
                psum[j] += v;
                pssq[j] += v * v;
            }
#pragma unroll
    for (int j = 0; j < 4; ++j) {
        psum[j] += __shfl_xor(psum[j], 16, 64);
        psum[j] += __shfl_xor(psum[j], 32, 64);
        pssq[j] += __shfl_xor(pssq[j], 16, 64);
        pssq[j] += __shfl_xor(pssq[j], 32, 64);
    }
    if (quad == 0) {
#pragma unroll
        for (int j = 0; j < 4; ++j) {
            int ccL = wn * 64 + j * 16 + l16;
            sred[wm][0][ccL] = psum[j];
            sred[wm][1][ccL] = pssq[j];
        }
    }
    __syncthreads();
    if (tid < 128) {
        float s  = sred[0][0][tid] + sred[1][0][tid];
        float ss = sred[0][1][tid] + sred[1][1][tid];
        float m  = s * (1.f / 128.f);
        float var = ss * (1.f / 128.f) - m * m;
        float rstd = rsqrtf(var + 1e-5f);
        int g = row0 >> 7;
        int col = col0 + tid;
        float a = rstd * gamma[col];
        float b = beta[col] - m * a;
        scale_o[(size_t)g * N + col] = a;
        shift_o[(size_t)g * N + col] = b;
    }
}

// ---------------------------------------------------------------------------
// Fast GEMM: bf16 inputs, m97 structure (global_load_lds width=16, unpadded
// 64B LDS rows), fused stats epilogue.  C = A @ W^T
// ---------------------------------------------------------------------------
__global__ __launch_bounds__(256) void gemm_bf16_kernel(
    const __bf16* __restrict__ A, const __bf16* __restrict__ W,
    float* __restrict__ C, float* __restrict__ scale_o, float* __restrict__ shift_o,
    const float* __restrict__ gamma, const float* __restrict__ beta,
    int M, int N, int K)
{
    __shared__ __align__(16) __bf16 As[TILE_M * TILE_K];
    __shared__ __align__(16) __bf16 Bs[TILE_N * TILE_K];
    __shared__ float sred[2][2][128];

    const int tid  = threadIdx.x;
    const int lane = tid & 63;
    const int wave = tid >> 6;
    const int wm   = wave >> 1;
    const int wn   = wave & 1;
    const int quad = lane >> 4;
    const int l16  = lane & 15;

    const int row0 = blockIdx.y * TILE_M;
    const int col0 = blockIdx.x * TILE_N;

    const int srow = lane >> 2;
    const int skof = (lane & 3) * 8;

    f32x4 acc[4][4];
#pragma unroll
    for (int i = 0; i < 4; ++i)
#pragma unroll
        for (int j = 0; j < 4; ++j) {
            f32x4 z = {0.f, 0.f, 0.f, 0.f};
            acc[i][j] = z;
        }

    for (int k0 = 0; k0 < K; k0 += TILE_K) {
        __syncthreads();
#pragma unroll
        for (int c = 0; c < 2; ++c) {
            int rbase = wave * 32 + c * 16;
            const __bf16* ga = &A[(size_t)(row0 + rbase + srow) * K + k0 + skof];
            const __bf16* gb = &W[(size_t)(col0 + rbase + srow) * K + k0 + skof];
            GLD16(ga, &As[rbase * TILE_K]);
            GLD16(gb, &Bs[rbase * TILE_K]);
        }
        __syncthreads();

        bf16x8 af[4], bfv[4];
#pragma unroll
        for (int i = 0; i < 4; ++i)
            af[i]  = *(const bf16x8*)&As[(wm * 64 + i * 16 + l16) * TILE_K + quad * 8];
#pragma unroll
        for (int j = 0; j < 4; ++j)
            bfv[j] = *(const bf16x8*)&Bs[(wn * 64 + j * 16 + l16) * TILE_K + quad * 8];

#pragma unroll
        for (int i = 0; i < 4; ++i)
#pragma unroll
            for (int j = 0; j < 4; ++j)
                acc[i][j] = __builtin_amdgcn_mfma_f32_16x16x32_bf16(af[i], bfv[j], acc[i][j], 0, 0, 0);
    }

    epilogue_fused_stats(acc, C, scale_o, shift_o, gamma, beta, sred,
                         row0, col0, N, wm, wn, quad, l16, tid);
}

// ---------------------------------------------------------------------------
// Fallback GEMM (ws too small for bf16 copies): fp32 inputs, in-kernel convert
// ---------------------------------------------------------------------------
#define LDSS 40
__global__ __launch_bounds__(256) void gemm_f32_kernel(
    const float* __restrict__ A, const float* __restrict__ W,
    float* __restrict__ C, float* __restrict__ scale_o, float* __restrict__ shift_o,
    const float* __restrict__ gamma, const float* __restrict__ beta,
    int M, int N, int K)
{
    __shared__ __align__(16) __bf16 As[TILE_M * LDSS];
    __shared__ __align__(16) __bf16 Bs[TILE_N * LDSS];
    __shared__ float sred[2][2][128];

    const int tid  = threadIdx.x;
    const int lane = tid & 63;
    const int wave = tid >> 6;
    const int wm   = wave >> 1;
    const int wn   = wave & 1;
    const int quad = lane >> 4;
    const int l16  = lane & 15;

    const int row0 = blockIdx.y * TILE_M;
    const int col0 = blockIdx.x * TILE_N;

    f32x4 acc[4][4];
#pragma unroll
    for (int i = 0; i < 4; ++i)
#pragma unroll
        for (int j = 0; j < 4; ++j) {
            f32x4 z = {0.f, 0.f, 0.f, 0.f};
            acc[i][j] = z;
        }

    for (int k0 = 0; k0 < K; k0 += TILE_K) {
        __syncthreads();
#pragma unroll
        for (int i = 0; i < 4; ++i) {
            int chunk = tid + i * 256;
            int r  = chunk >> 3;
            int c4 = chunk & 7;
            float4 av = *(const float4*)&A[(size_t)(row0 + r) * K + k0 + c4 * 4];
            float4 bv = *(const float4*)&W[(size_t)(col0 + r) * K + k0 + c4 * 4];
            bf16x4 a16 = { (__bf16)av.x, (__bf16)av.y, (__bf16)av.z, (__bf16)av.w };
            bf16x4 b16 = { (__bf16)bv.x, (__bf16)bv.y, (__bf16)bv.z, (__bf16)bv.w };
            *(bf16x4*)&As[r * LDSS + c4 * 4] = a16;
            *(bf16x4*)&Bs[r * LDSS + c4 * 4] = b16;
        }
        __syncthreads();

        bf16x8 af[4], bfv[4];
#pragma unroll
        for (int i = 0; i < 4; ++i)
            af[i]  = *(const bf16x8*)&As[(wm * 64 + i * 16 + l16) * LDSS + quad * 8];
#pragma unroll
        for (int j = 0; j < 4; ++j)
            bfv[j] = *(const bf16x8*)&Bs[(wn * 64 + j * 16 + l16) * LDSS + quad * 8];

#pragma unroll
        for (int i = 0; i < 4; ++i)
#pragma unroll
            for (int j = 0; j < 4; ++j)
                acc[i][j] = __builtin_amdgcn_mfma_f32_16x16x32_bf16(af[i], bfv[j], acc[i][j], 0, 0, 0);
    }

    epilogue_fused_stats(acc, C, scale_o, shift_o, gamma, beta, sred,
                         row0, col0, N, wm, wn, quad, l16, tid);
}

// ---------------------------------------------------------------------------
// BN-apply (pre-folded scale/shift) * priors -> sparsemax, 1 wave / row.
// Fixed-cost exact path: tau >= zmax-1 bound -> candidate compaction ->
// 64-lane bitonic sort + cumsum (replicates reference arithmetic).
// ---------------------------------------------------------------------------
__device__ __forceinline__ float waveReduceSum(float v) {
#pragma unroll
    for (int m = 1; m < 64; m <<= 1) v += __shfl_xor(v, m, 64);
    return v;
}
__device__ __forceinline__ float waveReduceMax(float v) {
#pragma unroll
    for (int m = 1; m < 64; m <<= 1) v = fmaxf(v, __shfl_xor(v, m, 64));
    return v;
}

__global__ __launch_bounds__(256) void bn_sparsemax_kernel(
    float* __restrict__ x,                // in: GEMM out; out: final (in-place)
    const float* __restrict__ priors,
    const float* __restrict__ scale_s,
    const float* __restrict__ shift_s,
    int N)
{
    __shared__ float cbuf[4][64];

    const int lane = threadIdx.x & 63;
    const int rib  = threadIdx.x >> 6;
    const int row  = blockIdx.x * 4 + rib;
    const int g    = row >> 7;            // VBS = 128
    const size_t base = (size_t)row * N;
    float* buf = cbuf[rib];

    float z[32];
#pragma unroll
    for (int j = 0; j < 8; ++j) {
        int c = j * 256 + lane * 4;
        float4 xv = *(const float4*)&x[base + c];
        float4 pv = *(const float4*)&priors[base + c];
        float4 av = *(const float4*)&scale_s[(size_t)g * N + c];
        float4 bv = *(const float4*)&shift_s[(size_t)g * N + c];
        z[j * 4 + 0] = fmaf(xv.x, av.x, bv.x) * pv.x;
        z[j * 4 + 1] = fmaf(xv.y, av.y, bv.y) * pv.y;
        z[j * 4 + 2] = fmaf(xv.z, av.z, bv.z) * pv.z;
        z[j * 4 + 3] = fmaf(xv.w, av.w, bv.w) * pv.w;
    }

    // wave max
    float mx = z[0];
#pragma unroll
    for (int i = 1; i < 32; ++i) mx = fmaxf(mx, z[i]);
    mx = waveReduceMax(mx);
    const float thresh = mx - 1.0f;       // tau >= zmax-1 always (max prob <= 1)

    // candidate count + exclusive prefix over lanes
    int ci = 0;
#pragma unroll
    for (int i = 0; i < 32; ++i) ci += (z[i] > thresh) ? 1 : 0;
    int scan = ci;
#pragma unroll
    for (int d = 1; d < 64; d <<= 1) {
        int t = __shfl_up(scan, d, 64);
        if (lane >= d) scan += t;
    }
    const int total = __shfl(scan, 63, 64);   // wave-uniform
    float tau;

    if (total <= 64) {
        // pad then compact candidates (distinct slots; same-wave DS is in-order)
        if (lane >= total) buf[lane] = -1e30f;
        int o = scan - ci;
#pragma unroll
        for (int i = 0; i < 32; ++i) {
            if (z[i] > thresh) { buf[o] = z[i]; ++o; }
        }
        __builtin_amdgcn_wave_barrier();
        float v = buf[lane];

        // 64-lane bitonic sort, descending
#pragma unroll
        for (int k = 2; k <= 64; k <<= 1) {
#pragma unroll
            for (int j = k >> 1; j > 0; j >>= 1) {
                float other = __shfl_xor(v, j, 64);
                bool up    = (lane & k) == 0;
                bool lower = (lane & j) == 0;
                float mn = fminf(v, other), mxx = fmaxf(v, other);
                v = (up ^ lower) ? mn : mxx;
            }
        }
        // inclusive cumsum over sorted values
        float cs = v;
#pragma unroll
        for (int d = 1; d < 64; d <<= 1) {
            float t = __shfl_up(cs, d, 64);
            if (lane >= d) cs += t;
        }
        // support condition (reference: 1 + k*z_sorted > cumsum)
        bool flag = (1.0f + (float)(lane + 1) * v) > cs;
        unsigned long long bal = __ballot(flag);
        int ks = __popcll(bal);
        float cs_k = __shfl(cs, ks - 1, 64);
        tau = (cs_k - 1.0f) / (float)ks;
    } else {
        // rare fallback: Michelot iteration (exact at fixed point)
        float s0 = 0.f;
#pragma unroll
        for (int i = 0; i < 32; ++i) s0 += z[i];
        s0 = waveReduceSum(s0);
        tau = (s0 - 1.0f) / (float)N;
        float kprev = (float)N;
        for (int it = 0; it < 64; ++it) {
            float s = 0.f, c = 0.f;
#pragma unroll
            for (int i = 0; i < 32; ++i) {
                bool m = z[i] > tau;
                s += m ? z[i] : 0.f;
                c += m ? 1.f  : 0.f;
            }
            s = waveReduceSum(s);
            c = waveReduceSum(c);
            float tnew = (s - 1.0f) / c;
            bool done = (c == kprev);
            kprev = c;
            tau = tnew;
            if (done) break;
        }
    }

#pragma unroll
    for (int j = 0; j < 8; ++j) {
        int c = j * 256 + lane * 4;
        float4 o;
        o.x = fmaxf(z[j * 4 + 0] - tau, 0.f);
        o.y = fmaxf(z[j * 4 + 1] - tau, 0.f);
        o.z = fmaxf(z[j * 4 + 2] - tau, 0.f);
        o.w = fmaxf(z[j * 4 + 3] - tau, 0.f);
        *(float4*)&x[base + c] = o;
    }
}

// ---------------------------------------------------------------------------
extern "C" void kernel_launch(void* const* d_in, const int* in_sizes, int n_in,
                              void* d_out, int out_size, void* d_ws, size_t ws_size,
                              hipStream_t stream)
{
    const float* priors = (const float*)d_in[0];
    const float* feat   = (const float*)d_in[1];
    const float* fc_w   = (const float*)d_in[2];
    const float* gamma  = (const float*)d_in[3];
    const float* beta   = (const float*)d_in[4];
    float* out = (float*)d_out;

    const int G = in_sizes[3];               // 2048
    const int K = in_sizes[2] / G;           // 2048
    const int B = in_sizes[1] / K;           // 16384
    const int nGroups = B / 128;             // 128

    const size_t statsElems = (size_t)nGroups * G;
    float* scale_s = (float*)d_ws;
    float* shift_s = scale_s + statsElems;
    char* wsAfterStats = (char*)(shift_s + statsElems);

    const size_t nFeat = (size_t)B * K;
    const size_t nW    = (size_t)G * K;
    const size_t needFast = 2 * statsElems * sizeof(float) + (nFeat + nW) * sizeof(__bf16);

    if (ws_size >= needFast) {
        __bf16* featb = (__bf16*)wsAfterStats;
        __bf16* wb    = featb + nFeat;
        long totalChunks = (long)((nFeat + nW) / 8);
        convert_kernel<<<(totalChunks + 255) / 256, 256, 0, stream>>>(
            feat, fc_w, featb, wb, (long)nFeat, (long)nW);
        gemm_bf16_kernel<<<dim3(G / TILE_N, B / TILE_M), 256, 0, stream>>>(
            featb, wb, out, scale_s, shift_s, gamma, beta, B, G, K);
    } else {
        gemm_f32_kernel<<<dim3(G / TILE_N, B / TILE_M), 256, 0, stream>>>(
            feat, fc_w, out, scale_s, shift_s, gamma, beta, B, G, K);
    }
    bn_sparsemax_kernel<<<B / 4, 256, 0, stream>>>(out, priors, scale_s, shift_s, G);
}

// Round 4
// 531.770 us; speedup vs baseline: 1.2050x; 1.0020x over previous
//
#include <hip/hip_runtime.h>

typedef __bf16 bf16x4 __attribute__((ext_vector_type(4)));
typedef __bf16 bf16x8 __attribute__((ext_vector_type(8)));
typedef float  f32x4  __attribute__((ext_vector_type(4)));

#define GLD16(gp, lp) __builtin_amdgcn_global_load_lds( \
    (const __attribute__((address_space(1))) void*)(gp), \
    (__attribute__((address_space(3))) void*)(lp), 16, 0, 0)

#define TILE_M 128
#define TILE_N 128
#define TILE_K 32

// ---------------------------------------------------------------------------
// fp32 -> bf16 one-shot convert (feat then fc_w, one grid)
// ---------------------------------------------------------------------------
__global__ __launch_bounds__(256) void convert_kernel(
    const float* __restrict__ feat, const float* __restrict__ w,
    __bf16* __restrict__ featb, __bf16* __restrict__ wb,
    long nFeat, long nW)
{
    long i = ((long)blockIdx.x * 256 + threadIdx.x) * 8;
    if (i < nFeat) {
        float4 a = *(const float4*)&feat[i];
        float4 b = *(const float4*)&feat[i + 4];
        bf16x8 o = {(__bf16)a.x,(__bf16)a.y,(__bf16)a.z,(__bf16)a.w,
                    (__bf16)b.x,(__bf16)b.y,(__bf16)b.z,(__bf16)b.w};
        *(bf16x8*)&featb[i] = o;
    } else {
        long j = i - nFeat;
        if (j < nW) {
            float4 a = *(const float4*)&w[j];
            float4 b = *(const float4*)&w[j + 4];
            bf16x8 o = {(__bf16)a.x,(__bf16)a.y,(__bf16)a.z,(__bf16)a.w,
                        (__bf16)b.x,(__bf16)b.y,(__bf16)b.z,(__bf16)b.w};
            *(bf16x8*)&wb[j] = o;
        }
    }
}

// ---------------------------------------------------------------------------
// Shared epilogue: write C tile + fused ghost-BN stats -> scale/shift
// (TILE_M == VBS == 128, so each block covers one full virtual batch slice)
// ---------------------------------------------------------------------------
__device__ __forceinline__ void epilogue_fused_stats(
    f32x4 (&acc)[4][4], float* __restrict__ C,
    float* __restrict__ scale_o, float* __restrict__ shift_o,
    const float* __restrict__ gamma, const float* __restrict__ beta,
    float (*sred)[2][128],
    int row0, int col0, int N, int wm, int wn, int quad, int l16, int tid)
{
    float psum[4] = {0,0,0,0}, pssq[4] = {0,0,0,0};
#pragma unroll
    for (int i = 0; i < 4; ++i)
#pragma unroll
        for (int j = 0; j < 4; ++j)
#pragma unroll
            for (int r = 0; r < 4; ++r) {
                float v = acc[i][j][r];
                int rr = row0 + wm * 64 + i * 16 + quad * 4 + r;
                int cc = col0 + wn * 64 + j * 16 + l16;
                C[(size_t)rr * N + cc] = v;
                psum[j] += v;
                pssq[j] += v * v;
            }
#pragma unroll
    for (int j = 0; j < 4; ++j) {
        psum[j] += __shfl_xor(psum[j], 16, 64);
        psum[j] += __shfl_xor(psum[j], 32, 64);
        pssq[j] += __shfl_xor(pssq[j], 16, 64);
        pssq[j] += __shfl_xor(pssq[j], 32, 64);
    }
    if (quad == 0) {
#pragma unroll
        for (int j = 0; j < 4; ++j) {
            int ccL = wn * 64 + j * 16 + l16;
            sred[wm][0][ccL] = psum[j];
            sred[wm][1][ccL] = pssq[j];
        }
    }
    __syncthreads();
    if (tid < 128) {
        float s  = sred[0][0][tid] + sred[1][0][tid];
        float ss = sred[0][1][tid] + sred[1][1][tid];
        float m  = s * (1.f / 128.f);
        float var = ss * (1.f / 128.f) - m * m;
        float rstd = rsqrtf(var + 1e-5f);
        int g = row0 >> 7;
        int col = col0 + tid;
        float a = rstd * gamma[col];
        float b = beta[col] - m * a;
        scale_o[(size_t)g * N + col] = a;
        shift_o[(size_t)g * N + col] = b;
    }
}

// ---------------------------------------------------------------------------
// Fast GEMM: bf16 inputs, m97 structure (global_load_lds width=16, unpadded
// 64B LDS rows), fused stats epilogue.  C = A @ W^T
// ---------------------------------------------------------------------------
__global__ __launch_bounds__(256) void gemm_bf16_kernel(
    const __bf16* __restrict__ A, const __bf16* __restrict__ W,
    float* __restrict__ C, float* __restrict__ scale_o, float* __restrict__ shift_o,
    const float* __restrict__ gamma, const float* __restrict__ beta,
    int M, int N, int K)
{
    __shared__ __align__(16) __bf16 As[TILE_M * TILE_K];
    __shared__ __align__(16) __bf16 Bs[TILE_N * TILE_K];
    __shared__ float sred[2][2][128];

    const int tid  = threadIdx.x;
    const int lane = tid & 63;
    const int wave = tid >> 6;
    const int wm   = wave >> 1;
    const int wn   = wave & 1;
    const int quad = lane >> 4;
    const int l16  = lane & 15;

    const int row0 = blockIdx.y * TILE_M;
    const int col0 = blockIdx.x * TILE_N;

    const int srow = lane >> 2;
    const int skof = (lane & 3) * 8;

    f32x4 acc[4][4];
#pragma unroll
    for (int i = 0; i < 4; ++i)
#pragma unroll
        for (int j = 0; j < 4; ++j) {
            f32x4 z = {0.f, 0.f, 0.f, 0.f};
            acc[i][j] = z;
        }

    for (int k0 = 0; k0 < K; k0 += TILE_K) {
        __syncthreads();
#pragma unroll
        for (int c = 0; c < 2; ++c) {
            int rbase = wave * 32 + c * 16;
            const __bf16* ga = &A[(size_t)(row0 + rbase + srow) * K + k0 + skof];
            const __bf16* gb = &W[(size_t)(col0 + rbase + srow) * K + k0 + skof];
            GLD16(ga, &As[rbase * TILE_K]);
            GLD16(gb, &Bs[rbase * TILE_K]);
        }
        __syncthreads();

        bf16x8 af[4], bfv[4];
#pragma unroll
        for (int i = 0; i < 4; ++i)
            af[i]  = *(const bf16x8*)&As[(wm * 64 + i * 16 + l16) * TILE_K + quad * 8];
#pragma unroll
        for (int j = 0; j < 4; ++j)
            bfv[j] = *(const bf16x8*)&Bs[(wn * 64 + j * 16 + l16) * TILE_K + quad * 8];

#pragma unroll
        for (int i = 0; i < 4; ++i)
#pragma unroll
            for (int j = 0; j < 4; ++j)
                acc[i][j] = __builtin_amdgcn_mfma_f32_16x16x32_bf16(af[i], bfv[j], acc[i][j], 0, 0, 0);
    }

    epilogue_fused_stats(acc, C, scale_o, shift_o, gamma, beta, sred,
                         row0, col0, N, wm, wn, quad, l16, tid);
}

// ---------------------------------------------------------------------------
// Fallback GEMM (ws too small for bf16 copies): fp32 inputs, in-kernel convert
// ---------------------------------------------------------------------------
#define LDSS 40
__global__ __launch_bounds__(256) void gemm_f32_kernel(
    const float* __restrict__ A, const float* __restrict__ W,
    float* __restrict__ C, float* __restrict__ scale_o, float* __restrict__ shift_o,
    const float* __restrict__ gamma, const float* __restrict__ beta,
    int M, int N, int K)
{
    __shared__ __align__(16) __bf16 As[TILE_M * LDSS];
    __shared__ __align__(16) __bf16 Bs[TILE_N * LDSS];
    __shared__ float sred[2][2][128];

    const int tid  = threadIdx.x;
    const int lane = tid & 63;
    const int wave = tid >> 6;
    const int wm   = wave >> 1;
    const int wn   = wave & 1;
    const int quad = lane >> 4;
    const int l16  = lane & 15;

    const int row0 = blockIdx.y * TILE_M;
    const int col0 = blockIdx.x * TILE_N;

    f32x4 acc[4][4];
#pragma unroll
    for (int i = 0; i < 4; ++i)
#pragma unroll
        for (int j = 0; j < 4; ++j) {
            f32x4 z = {0.f, 0.f, 0.f, 0.f};
            acc[i][j] = z;
        }

    for (int k0 = 0; k0 < K; k0 += TILE_K) {
        __syncthreads();
#pragma unroll
        for (int i = 0; i < 4; ++i) {
            int chunk = tid + i * 256;
            int r  = chunk >> 3;
            int c4 = chunk & 7;
            float4 av = *(const float4*)&A[(size_t)(row0 + r) * K + k0 + c4 * 4];
            float4 bv = *(const float4*)&W[(size_t)(col0 + r) * K + k0 + c4 * 4];
            bf16x4 a16 = { (__bf16)av.x, (__bf16)av.y, (__bf16)av.z, (__bf16)av.w };
            bf16x4 b16 = { (__bf16)bv.x, (__bf16)bv.y, (__bf16)bv.z, (__bf16)bv.w };
            *(bf16x4*)&As[r * LDSS + c4 * 4] = a16;
            *(bf16x4*)&Bs[r * LDSS + c4 * 4] = b16;
        }
        __syncthreads();

        bf16x8 af[4], bfv[4];
#pragma unroll
        for (int i = 0; i < 4; ++i)
            af[i]  = *(const bf16x8*)&As[(wm * 64 + i * 16 + l16) * LDSS + quad * 8];
#pragma unroll
        for (int j = 0; j < 4; ++j)
            bfv[j] = *(const bf16x8*)&Bs[(wn * 64 + j * 16 + l16) * LDSS + quad * 8];

#pragma unroll
        for (int i = 0; i < 4; ++i)
#pragma unroll
            for (int j = 0; j < 4; ++j)
                acc[i][j] = __builtin_amdgcn_mfma_f32_16x16x32_bf16(af[i], bfv[j], acc[i][j], 0, 0, 0);
    }

    epilogue_fused_stats(acc, C, scale_o, shift_o, gamma, beta, sred,
                         row0, col0, N, wm, wn, quad, l16, tid);
}

// ---------------------------------------------------------------------------
// BN-apply (pre-folded scale/shift) * priors -> sparsemax.
// ONE BLOCK (256 thr) PER ROW, 8 elems/lane: low VGPR -> high occupancy ->
// HBM-latency hiding. Michelot warm-started at tau0 = zmax-1 (valid lower
// bound since max output prob <= 1) -> ~3-5 iterations.
// Requires N == 2048.
// ---------------------------------------------------------------------------
__global__ __launch_bounds__(256) void bn_sparsemax_kernel(
    float* __restrict__ x,                // in: GEMM out; out: final (in-place)
    const float* __restrict__ priors,
    const float* __restrict__ scale_s,
    const float* __restrict__ shift_s,
    int N)
{
    __shared__ float red[2][4][2];   // [iter parity][wave][sum, count]
    __shared__ float mred[4];

    const int tid  = threadIdx.x;
    const int lane = tid & 63;
    const int wave = tid >> 6;
    const int row  = blockIdx.x;
    const int g    = row >> 7;            // VBS = 128
    const size_t base  = (size_t)row * N;
    const size_t gbase = (size_t)g * N;
    const int c0 = tid * 4;               // first half slot
    const int c1 = 1024 + tid * 4;        // second half slot (order-invariant split)

    // 12 independent float4 loads, perfectly coalesced
    float4 x0 = *(const float4*)&x[base + c0];
    float4 x1 = *(const float4*)&x[base + c1];
    float4 p0 = *(const float4*)&priors[base + c0];
    float4 p1 = *(const float4*)&priors[base + c1];
    float4 a0 = *(const float4*)&scale_s[gbase + c0];
    float4 a1 = *(const float4*)&scale_s[gbase + c1];
    float4 b0 = *(const float4*)&shift_s[gbase + c0];
    float4 b1 = *(const float4*)&shift_s[gbase + c1];

    float z[8];
    z[0] = fmaf(x0.x, a0.x, b0.x) * p0.x;
    z[1] = fmaf(x0.y, a0.y, b0.y) * p0.y;
    z[2] = fmaf(x0.z, a0.z, b0.z) * p0.z;
    z[3] = fmaf(x0.w, a0.w, b0.w) * p0.w;
    z[4] = fmaf(x1.x, a1.x, b1.x) * p1.x;
    z[5] = fmaf(x1.y, a1.y, b1.y) * p1.y;
    z[6] = fmaf(x1.z, a1.z, b1.z) * p1.z;
    z[7] = fmaf(x1.w, a1.w, b1.w) * p1.w;

    // block max
    float mx = z[0];
#pragma unroll
    for (int i = 1; i < 8; ++i) mx = fmaxf(mx, z[i]);
#pragma unroll
    for (int m = 1; m < 64; m <<= 1) mx = fmaxf(mx, __shfl_xor(mx, m, 64));
    if (lane == 0) mred[wave] = mx;
    __syncthreads();
    mx = fmaxf(fmaxf(mred[0], mred[1]), fmaxf(mred[2], mred[3]));

    // Michelot from tau0 = zmax - 1 (support starts at the small candidate set)
    float tau   = mx - 1.0f;
    float kprev = -1.0f;
    for (int it = 0; it < 32; ++it) {
        float s = 0.f, c = 0.f;
#pragma unroll
        for (int i = 0; i < 8; ++i) {
            bool m = z[i] > tau;
            s += m ? z[i] : 0.f;
            c += m ? 1.f  : 0.f;
        }
#pragma unroll
        for (int m = 1; m < 64; m <<= 1) {
            s += __shfl_xor(s, m, 64);
            c += __shfl_xor(c, m, 64);
        }
        if (lane == 0) { red[it & 1][wave][0] = s; red[it & 1][wave][1] = c; }
        __syncthreads();
        s = red[it & 1][0][0] + red[it & 1][1][0] + red[it & 1][2][0] + red[it & 1][3][0];
        c = red[it & 1][0][1] + red[it & 1][1][1] + red[it & 1][2][1] + red[it & 1][3][1];
        float tnew = (s - 1.0f) / c;
        bool done = (c == kprev);     // block-uniform (from reduced values)
        kprev = c;
        tau = tnew;
        if (done) break;              // support unchanged -> tau exact
    }

    float4 o0, o1;
    o0.x = fmaxf(z[0] - tau, 0.f);
    o0.y = fmaxf(z[1] - tau, 0.f);
    o0.z = fmaxf(z[2] - tau, 0.f);
    o0.w = fmaxf(z[3] - tau, 0.f);
    o1.x = fmaxf(z[4] - tau, 0.f);
    o1.y = fmaxf(z[5] - tau, 0.f);
    o1.z = fmaxf(z[6] - tau, 0.f);
    o1.w = fmaxf(z[7] - tau, 0.f);
    *(float4*)&x[base + c0] = o0;
    *(float4*)&x[base + c1] = o1;
}

// ---------------------------------------------------------------------------
extern "C" void kernel_launch(void* const* d_in, const int* in_sizes, int n_in,
                              void* d_out, int out_size, void* d_ws, size_t ws_size,
                              hipStream_t stream)
{
    const float* priors = (const float*)d_in[0];
    const float* feat   = (const float*)d_in[1];
    const float* fc_w   = (const float*)d_in[2];
    const float* gamma  = (const float*)d_in[3];
    const float* beta   = (const float*)d_in[4];
    float* out = (float*)d_out;

    const int G = in_sizes[3];               // 2048
    const int K = in_sizes[2] / G;           // 2048
    const int B = in_sizes[1] / K;           // 16384
    const int nGroups = B / 128;             // 128

    const size_t statsElems = (size_t)nGroups * G;
    float* scale_s = (float*)d_ws;
    float* shift_s = scale_s + statsElems;
    char* wsAfterStats = (char*)(shift_s + statsElems);

    const size_t nFeat = (size_t)B * K;
    const size_t nW    = (size_t)G * K;
    const size_t needFast = 2 * statsElems * sizeof(float) + (nFeat + nW) * sizeof(__bf16);

    if (ws_size >= needFast) {
        __bf16* featb = (__bf16*)wsAfterStats;
        __bf16* wb    = featb + nFeat;
        long totalChunks = (long)((nFeat + nW) / 8);
        convert_kernel<<<(totalChunks + 255) / 256, 256, 0, stream>>>(
            feat, fc_w, featb, wb, (long)nFeat, (long)nW);
        gemm_bf16_kernel<<<dim3(G / TILE_N, B / TILE_M), 256, 0, stream>>>(
            featb, wb, out, scale_s, shift_s, gamma, beta, B, G, K);
    } else {
        gemm_f32_kernel<<<dim3(G / TILE_N, B / TILE_M), 256, 0, stream>>>(
            feat, fc_w, out, scale_s, shift_s, gamma, beta, B, G, K);
    }
    bn_sparsemax_kernel<<<B, 256, 0, stream>>>(out, priors, scale_s, shift_s, G);
}

// Round 5
// 520.215 us; speedup vs baseline: 1.2318x; 1.0222x over previous
//
#include <hip/hip_runtime.h>

typedef __bf16 bf16x4 __attribute__((ext_vector_type(4)));
typedef __bf16 bf16x8 __attribute__((ext_vector_type(8)));
typedef float  f32x4  __attribute__((ext_vector_type(4)));

#define GLD16(gp, lp) __builtin_amdgcn_global_load_lds( \
    (const __attribute__((address_space(1))) void*)(gp), \
    (__attribute__((address_space(3))) void*)(lp), 16, 0, 0)

#define TILE_M 128
#define TILE_N 128

// ---------------------------------------------------------------------------
// fp32 -> bf16 one-shot convert (feat then fc_w, one grid)
// ---------------------------------------------------------------------------
__global__ __launch_bounds__(256) void convert_kernel(
    const float* __restrict__ feat, const float* __restrict__ w,
    __bf16* __restrict__ featb, __bf16* __restrict__ wb,
    long nFeat, long nW)
{
    long i = ((long)blockIdx.x * 256 + threadIdx.x) * 8;
    if (i < nFeat) {
        float4 a = *(const float4*)&feat[i];
        float4 b = *(const float4*)&feat[i + 4];
        bf16x8 o = {(__bf16)a.x,(__bf16)a.y,(__bf16)a.z,(__bf16)a.w,
                    (__bf16)b.x,(__bf16)b.y,(__bf16)b.z,(__bf16)b.w};
        *(bf16x8*)&featb[i] = o;
    } else {
        long j = i - nFeat;
        if (j < nW) {
            float4 a = *(const float4*)&w[j];
            float4 b = *(const float4*)&w[j + 4];
            bf16x8 o = {(__bf16)a.x,(__bf16)a.y,(__bf16)a.z,(__bf16)a.w,
                        (__bf16)b.x,(__bf16)b.y,(__bf16)b.z,(__bf16)b.w};
            *(bf16x8*)&wb[j] = o;
        }
    }
}

// ---------------------------------------------------------------------------
// Shared epilogue: write C tile + fused ghost-BN stats -> scale/shift
// (TILE_M == VBS == 128, so each block covers one full virtual batch slice)
// ---------------------------------------------------------------------------
__device__ __forceinline__ void epilogue_fused_stats(
    f32x4 (&acc)[4][4], float* __restrict__ C,
    float* __restrict__ scale_o, float* __restrict__ shift_o,
    const float* __restrict__ gamma, const float* __restrict__ beta,
    float (*sred)[2][128],
    int row0, int col0, int N, int wm, int wn, int quad, int l16, int tid)
{
    float psum[4] = {0,0,0,0}, pssq[4] = {0,0,0,0};
#pragma unroll
    for (int i = 0; i < 4; ++i)
#pragma unroll
        for (int j = 0; j < 4; ++j)
#pragma unroll
            for (int r = 0; r < 4; ++r) {
                float v = acc[i][j][r];
                int rr = row0 + wm * 64 + i * 16 + quad * 4 + r;
                int cc = col0 + wn * 64 + j * 16 + l16;
                C[(size_t)rr * N + cc] = v;
                psum[j] += v;
                pssq[j] += v * v;
            }
#pragma unroll
    for (int j = 0; j < 4; ++j) {
        psum[j] += __shfl_xor(psum[j], 16, 64);
        psum[j] += __shfl_xor(psum[j], 32, 64);
        pssq[j] += __shfl_xor(pssq[j], 16, 64);
        pssq[j] += __shfl_xor(pssq[j], 32, 64);
    }
    if (quad == 0) {
#pragma unroll
        for (int j = 0; j < 4; ++j) {
            int ccL = wn * 64 + j * 16 + l16;
            sred[wm][0][ccL] = psum[j];
            sred[wm][1][ccL] = pssq[j];
        }
    }
    __syncthreads();
    if (tid < 128) {
        float s  = sred[0][0][tid] + sred[1][0][tid];
        float ss = sred[0][1][tid] + sred[1][1][tid];
        float m  = s * (1.f / 128.f);
        float var = ss * (1.f / 128.f) - m * m;
        float rstd = rsqrtf(var + 1e-5f);
        int g = row0 >> 7;
        int col = col0 + tid;
        float a = rstd * gamma[col];
        float b = beta[col] - m * a;
        scale_o[(size_t)g * N + col] = a;
        shift_o[(size_t)g * N + col] = b;
    }
}

// ---------------------------------------------------------------------------
// Fast GEMM: bf16 inputs, m97 staging (global_load_lds width=16, unpadded
// 64B LDS rows), BK=64 via two replicated BK=32 buffers: halves barrier
// count, 32 MFMA per barrier-pair. Fused stats epilogue.  C = A @ W^T
// ---------------------------------------------------------------------------
__global__ __launch_bounds__(256) void gemm_bf16_kernel(
    const __bf16* __restrict__ A, const __bf16* __restrict__ W,
    float* __restrict__ C, float* __restrict__ scale_o, float* __restrict__ shift_o,
    const float* __restrict__ gamma, const float* __restrict__ beta,
    int M, int N, int K)
{
    __shared__ __align__(16) __bf16 As[2][TILE_M * 32];   // 64B rows, NO pad
    __shared__ __align__(16) __bf16 Bs[2][TILE_N * 32];
    __shared__ float sred[2][2][128];

    const int tid  = threadIdx.x;
    const int lane = tid & 63;
    const int wave = tid >> 6;
    const int wm   = wave >> 1;
    const int wn   = wave & 1;
    const int quad = lane >> 4;
    const int l16  = lane & 15;

    const int row0 = blockIdx.y * TILE_M;
    const int col0 = blockIdx.x * TILE_N;

    const int srow = lane >> 2;          // 0..15: row within 16-row chunk
    const int skof = (lane & 3) * 8;     // bf16 elems within 32-wide k

    f32x4 acc[4][4];
#pragma unroll
    for (int i = 0; i < 4; ++i)
#pragma unroll
        for (int j = 0; j < 4; ++j) {
            f32x4 z = {0.f, 0.f, 0.f, 0.f};
            acc[i][j] = z;
        }

    for (int k0 = 0; k0 < K; k0 += 64) {
        __syncthreads();
        // wave stages rows [wave*32, wave*32+32) for both k-halves of A and B
#pragma unroll
        for (int h = 0; h < 2; ++h)
#pragma unroll
            for (int c = 0; c < 2; ++c) {
                int rbase = wave * 32 + c * 16;
                const __bf16* ga = &A[(size_t)(row0 + rbase + srow) * K + k0 + h * 32 + skof];
                const __bf16* gb = &W[(size_t)(col0 + rbase + srow) * K + k0 + h * 32 + skof];
                GLD16(ga, &As[h][rbase * 32]);
                GLD16(gb, &Bs[h][rbase * 32]);
            }
        __syncthreads();

#pragma unroll
        for (int h = 0; h < 2; ++h) {
            bf16x8 af[4], bfv[4];
#pragma unroll
            for (int i = 0; i < 4; ++i)
                af[i]  = *(const bf16x8*)&As[h][(wm * 64 + i * 16 + l16) * 32 + quad * 8];
#pragma unroll
            for (int j = 0; j < 4; ++j)
                bfv[j] = *(const bf16x8*)&Bs[h][(wn * 64 + j * 16 + l16) * 32 + quad * 8];

#pragma unroll
            for (int i = 0; i < 4; ++i)
#pragma unroll
                for (int j = 0; j < 4; ++j)
                    acc[i][j] = __builtin_amdgcn_mfma_f32_16x16x32_bf16(af[i], bfv[j], acc[i][j], 0, 0, 0);
        }
    }

    epilogue_fused_stats(acc, C, scale_o, shift_o, gamma, beta, sred,
                         row0, col0, N, wm, wn, quad, l16, tid);
}

// ---------------------------------------------------------------------------
// Fallback GEMM (ws too small for bf16 copies): fp32 inputs, in-kernel convert
// ---------------------------------------------------------------------------
#define LDSS 40
__global__ __launch_bounds__(256) void gemm_f32_kernel(
    const float* __restrict__ A, const float* __restrict__ W,
    float* __restrict__ C, float* __restrict__ scale_o, float* __restrict__ shift_o,
    const float* __restrict__ gamma, const float* __restrict__ beta,
    int M, int N, int K)
{
    __shared__ __align__(16) __bf16 As[TILE_M * LDSS];
    __shared__ __align__(16) __bf16 Bs[TILE_N * LDSS];
    __shared__ float sred[2][2][128];

    const int tid  = threadIdx.x;
    const int lane = tid & 63;
    const int wave = tid >> 6;
    const int wm   = wave >> 1;
    const int wn   = wave & 1;
    const int quad = lane >> 4;
    const int l16  = lane & 15;

    const int row0 = blockIdx.y * TILE_M;
    const int col0 = blockIdx.x * TILE_N;

    f32x4 acc[4][4];
#pragma unroll
    for (int i = 0; i < 4; ++i)
#pragma unroll
        for (int j = 0; j < 4; ++j) {
            f32x4 z = {0.f, 0.f, 0.f, 0.f};
            acc[i][j] = z;
        }

    for (int k0 = 0; k0 < K; k0 += 32) {
        __syncthreads();
#pragma unroll
        for (int i = 0; i < 4; ++i) {
            int chunk = tid + i * 256;
            int r  = chunk >> 3;
            int c4 = chunk & 7;
            float4 av = *(const float4*)&A[(size_t)(row0 + r) * K + k0 + c4 * 4];
            float4 bv = *(const float4*)&W[(size_t)(col0 + r) * K + k0 + c4 * 4];
            bf16x4 a16 = { (__bf16)av.x, (__bf16)av.y, (__bf16)av.z, (__bf16)av.w };
            bf16x4 b16 = { (__bf16)bv.x, (__bf16)bv.y, (__bf16)bv.z, (__bf16)bv.w };
            *(bf16x4*)&As[r * LDSS + c4 * 4] = a16;
            *(bf16x4*)&Bs[r * LDSS + c4 * 4] = b16;
        }
        __syncthreads();

        bf16x8 af[4], bfv[4];
#pragma unroll
        for (int i = 0; i < 4; ++i)
            af[i]  = *(const bf16x8*)&As[(wm * 64 + i * 16 + l16) * LDSS + quad * 8];
#pragma unroll
        for (int j = 0; j < 4; ++j)
            bfv[j] = *(const bf16x8*)&Bs[(wn * 64 + j * 16 + l16) * LDSS + quad * 8];

#pragma unroll
        for (int i = 0; i < 4; ++i)
#pragma unroll
            for (int j = 0; j < 4; ++j)
                acc[i][j] = __builtin_amdgcn_mfma_f32_16x16x32_bf16(af[i], bfv[j], acc[i][j], 0, 0, 0);
    }

    epilogue_fused_stats(acc, C, scale_o, shift_o, gamma, beta, sred,
                         row0, col0, N, wm, wn, quad, l16, tid);
}

// ---------------------------------------------------------------------------
// BN-apply (pre-folded scale/shift) * priors -> sparsemax.
// One 256-thr block per row, 8 elems/lane; Michelot warm-started at
// tau0 = zmax-1 (valid lower bound since max output prob <= 1).
// Requires N == 2048.
// ---------------------------------------------------------------------------
__global__ __launch_bounds__(256) void bn_sparsemax_kernel(
    float* __restrict__ x,                // in: GEMM out; out: final (in-place)
    const float* __restrict__ priors,
    const float* __restrict__ scale_s,
    const float* __restrict__ shift_s,
    int N)
{
    __shared__ float red[2][4][2];   // [iter parity][wave][sum, count]
    __shared__ float mred[4];

    const int tid  = threadIdx.x;
    const int lane = tid & 63;
    const int wave = tid >> 6;
    const int row  = blockIdx.x;
    const int g    = row >> 7;            // VBS = 128
    const size_t base  = (size_t)row * N;
    const size_t gbase = (size_t)g * N;
    const int c0 = tid * 4;
    const int c1 = 1024 + tid * 4;        // order-invariant split

    float4 x0 = *(const float4*)&x[base + c0];
    float4 x1 = *(const float4*)&x[base + c1];
    float4 p0 = *(const float4*)&priors[base + c0];
    float4 p1 = *(const float4*)&priors[base + c1];
    float4 a0 = *(const float4*)&scale_s[gbase + c0];
    float4 a1 = *(const float4*)&scale_s[gbase + c1];
    float4 b0 = *(const float4*)&shift_s[gbase + c0];
    float4 b1 = *(const float4*)&shift_s[gbase + c1];

    float z[8];
    z[0] = fmaf(x0.x, a0.x, b0.x) * p0.x;
    z[1] = fmaf(x0.y, a0.y, b0.y) * p0.y;
    z[2] = fmaf(x0.z, a0.z, b0.z) * p0.z;
    z[3] = fmaf(x0.w, a0.w, b0.w) * p0.w;
    z[4] = fmaf(x1.x, a1.x, b1.x) * p1.x;
    z[5] = fmaf(x1.y, a1.y, b1.y) * p1.y;
    z[6] = fmaf(x1.z, a1.z, b1.z) * p1.z;
    z[7] = fmaf(x1.w, a1.w, b1.w) * p1.w;

    float mx = z[0];
#pragma unroll
    for (int i = 1; i < 8; ++i) mx = fmaxf(mx, z[i]);
#pragma unroll
    for (int m = 1; m < 64; m <<= 1) mx = fmaxf(mx, __shfl_xor(mx, m, 64));
    if (lane == 0) mred[wave] = mx;
    __syncthreads();
    mx = fmaxf(fmaxf(mred[0], mred[1]), fmaxf(mred[2], mred[3]));

    float tau   = mx - 1.0f;
    float kprev = -1.0f;
    for (int it = 0; it < 32; ++it) {
        float s = 0.f, c = 0.f;
#pragma unroll
        for (int i = 0; i < 8; ++i) {
            bool m = z[i] > tau;
            s += m ? z[i] : 0.f;
            c += m ? 1.f  : 0.f;
        }
#pragma unroll
        for (int m = 1; m < 64; m <<= 1) {
            s += __shfl_xor(s, m, 64);
            c += __shfl_xor(c, m, 64);
        }
        if (lane == 0) { red[it & 1][wave][0] = s; red[it & 1][wave][1] = c; }
        __syncthreads();
        s = red[it & 1][0][0] + red[it & 1][1][0] + red[it & 1][2][0] + red[it & 1][3][0];
        c = red[it & 1][0][1] + red[it & 1][1][1] + red[it & 1][2][1] + red[it & 1][3][1];
        float tnew = (s - 1.0f) / c;
        bool done = (c == kprev);     // block-uniform (from reduced values)
        kprev = c;
        tau = tnew;
        if (done) break;              // support unchanged -> tau exact
    }

    float4 o0, o1;
    o0.x = fmaxf(z[0] - tau, 0.f);
    o0.y = fmaxf(z[1] - tau, 0.f);
    o0.z = fmaxf(z[2] - tau, 0.f);
    o0.w = fmaxf(z[3] - tau, 0.f);
    o1.x = fmaxf(z[4] - tau, 0.f);
    o1.y = fmaxf(z[5] - tau, 0.f);
    o1.z = fmaxf(z[6] - tau, 0.f);
    o1.w = fmaxf(z[7] - tau, 0.f);
    *(float4*)&x[base + c0] = o0;
    *(float4*)&x[base + c1] = o1;
}

// ---------------------------------------------------------------------------
extern "C" void kernel_launch(void* const* d_in, const int* in_sizes, int n_in,
                              void* d_out, int out_size, void* d_ws, size_t ws_size,
                              hipStream_t stream)
{
    const float* priors = (const float*)d_in[0];
    const float* feat   = (const float*)d_in[1];
    const float* fc_w   = (const float*)d_in[2];
    const float* gamma  = (const float*)d_in[3];
    const float* beta   = (const float*)d_in[4];
    float* out = (float*)d_out;

    const int G = in_sizes[3];               // 2048
    const int K = in_sizes[2] / G;           // 2048
    const int B = in_sizes[1] / K;           // 16384
    const int nGroups = B / 128;             // 128

    const size_t statsElems = (size_t)nGroups * G;
    float* scale_s = (float*)d_ws;
    float* shift_s = scale_s + statsElems;
    char* wsAfterStats = (char*)(shift_s + statsElems);

    const size_t nFeat = (size_t)B * K;
    const size_t nW    = (size_t)G * K;
    const size_t needFast = 2 * statsElems * sizeof(float) + (nFeat + nW) * sizeof(__bf16);

    if (ws_size >= needFast) {
        __bf16* featb = (__bf16*)wsAfterStats;
        __bf16* wb    = featb + nFeat;
        long totalChunks = (long)((nFeat + nW) / 8);
        convert_kernel<<<(totalChunks + 255) / 256, 256, 0, stream>>>(
            feat, fc_w, featb, wb, (long)nFeat, (long)nW);
        gemm_bf16_kernel<<<dim3(G / TILE_N, B / TILE_M), 256, 0, stream>>>(
            featb, wb, out, scale_s, shift_s, gamma, beta, B, G, K);
    } else {
        gemm_f32_kernel<<<dim3(G / TILE_N, B / TILE_M), 256, 0, stream>>>(
            feat, fc_w, out, scale_s, shift_s, gamma, beta, B, G, K);
    }
    bn_sparsemax_kernel<<<B, 256, 0, stream>>>(out, priors, scale_s, shift_s, G);
}

// Round 6
// 492.085 us; speedup vs baseline: 1.3022x; 1.0572x over previous
//
#include <hip/hip_runtime.h>

typedef __bf16 bf16x4 __attribute__((ext_vector_type(4)));
typedef __bf16 bf16x8 __attribute__((ext_vector_type(8)));
typedef float  f32x4  __attribute__((ext_vector_type(4)));

#define GLD16(gp, lp) __builtin_amdgcn_global_load_lds( \
    (const __attribute__((address_space(1))) void*)(gp), \
    (__attribute__((address_space(3))) void*)(lp), 16, 0, 0)

#define TILE_M 128
#define TILE_N 128

// ---------------------------------------------------------------------------
// fp32 -> bf16 one-shot convert (feat then fc_w, one grid)
// ---------------------------------------------------------------------------
__global__ __launch_bounds__(256) void convert_kernel(
    const float* __restrict__ feat, const float* __restrict__ w,
    __bf16* __restrict__ featb, __bf16* __restrict__ wb,
    long nFeat, long nW)
{
    long i = ((long)blockIdx.x * 256 + threadIdx.x) * 8;
    if (i < nFeat) {
        float4 a = *(const float4*)&feat[i];
        float4 b = *(const float4*)&feat[i + 4];
        bf16x8 o = {(__bf16)a.x,(__bf16)a.y,(__bf16)a.z,(__bf16)a.w,
                    (__bf16)b.x,(__bf16)b.y,(__bf16)b.z,(__bf16)b.w};
        *(bf16x8*)&featb[i] = o;
    } else {
        long j = i - nFeat;
        if (j < nW) {
            float4 a = *(const float4*)&w[j];
            float4 b = *(const float4*)&w[j + 4];
            bf16x8 o = {(__bf16)a.x,(__bf16)a.y,(__bf16)a.z,(__bf16)a.w,
                        (__bf16)b.x,(__bf16)b.y,(__bf16)b.z,(__bf16)b.w};
            *(bf16x8*)&wb[j] = o;
        }
    }
}

// ---------------------------------------------------------------------------
// Stats reduction part of the epilogue (shared by both store variants)
// ---------------------------------------------------------------------------
__device__ __forceinline__ void stats_reduce_store(
    float (&psum)[4], float (&pssq)[4],
    float* __restrict__ scale_o, float* __restrict__ shift_o,
    const float* __restrict__ gamma, const float* __restrict__ beta,
    float (*sred)[2][128],
    int row0, int col0, int N, int wm, int wn, int l16, int quad, int tid)
{
#pragma unroll
    for (int j = 0; j < 4; ++j) {
        psum[j] += __shfl_xor(psum[j], 16, 64);
        psum[j] += __shfl_xor(psum[j], 32, 64);
        pssq[j] += __shfl_xor(pssq[j], 16, 64);
        pssq[j] += __shfl_xor(pssq[j], 32, 64);
    }
    if (quad == 0) {
#pragma unroll
        for (int j = 0; j < 4; ++j) {
            int ccL = wn * 64 + j * 16 + l16;
            sred[wm][0][ccL] = psum[j];
            sred[wm][1][ccL] = pssq[j];
        }
    }
    __syncthreads();
    if (tid < 128) {
        float s  = sred[0][0][tid] + sred[1][0][tid];
        float ss = sred[0][1][tid] + sred[1][1][tid];
        float m  = s * (1.f / 128.f);
        float var = ss * (1.f / 128.f) - m * m;
        float rstd = rsqrtf(var + 1e-5f);
        int g = row0 >> 7;
        int col = col0 + tid;
        float a = rstd * gamma[col];
        float b = beta[col] - m * a;
        scale_o[(size_t)g * N + col] = a;
        shift_o[(size_t)g * N + col] = b;
    }
}

// ---------------------------------------------------------------------------
// Fast GEMM: bf16 inputs, m97 staging (global_load_lds width=16, unpadded
// 64B LDS rows), BK=64 via two replicated BK=32 buffers. Fused stats
// epilogue; x stored as BF16 (BN divides by sigma, so 0.2% rel rounding on x
// is ~0.002 on z — well under threshold).  C = A @ W^T
// ---------------------------------------------------------------------------
__global__ __launch_bounds__(256) void gemm_bf16_kernel(
    const __bf16* __restrict__ A, const __bf16* __restrict__ W,
    __bf16* __restrict__ Xb, float* __restrict__ scale_o, float* __restrict__ shift_o,
    const float* __restrict__ gamma, const float* __restrict__ beta,
    int M, int N, int K)
{
    __shared__ __align__(16) __bf16 As[2][TILE_M * 32];   // 64B rows, NO pad
    __shared__ __align__(16) __bf16 Bs[2][TILE_N * 32];
    __shared__ float sred[2][2][128];

    const int tid  = threadIdx.x;
    const int lane = tid & 63;
    const int wave = tid >> 6;
    const int wm   = wave >> 1;
    const int wn   = wave & 1;
    const int quad = lane >> 4;
    const int l16  = lane & 15;

    const int row0 = blockIdx.y * TILE_M;
    const int col0 = blockIdx.x * TILE_N;

    const int srow = lane >> 2;          // 0..15: row within 16-row chunk
    const int skof = (lane & 3) * 8;     // bf16 elems within 32-wide k

    f32x4 acc[4][4];
#pragma unroll
    for (int i = 0; i < 4; ++i)
#pragma unroll
        for (int j = 0; j < 4; ++j) {
            f32x4 z = {0.f, 0.f, 0.f, 0.f};
            acc[i][j] = z;
        }

    for (int k0 = 0; k0 < K; k0 += 64) {
        __syncthreads();
#pragma unroll
        for (int h = 0; h < 2; ++h)
#pragma unroll
            for (int c = 0; c < 2; ++c) {
                int rbase = wave * 32 + c * 16;
                const __bf16* ga = &A[(size_t)(row0 + rbase + srow) * K + k0 + h * 32 + skof];
                const __bf16* gb = &W[(size_t)(col0 + rbase + srow) * K + k0 + h * 32 + skof];
                GLD16(ga, &As[h][rbase * 32]);
                GLD16(gb, &Bs[h][rbase * 32]);
            }
        __syncthreads();

#pragma unroll
        for (int h = 0; h < 2; ++h) {
            bf16x8 af[4], bfv[4];
#pragma unroll
            for (int i = 0; i < 4; ++i)
                af[i]  = *(const bf16x8*)&As[h][(wm * 64 + i * 16 + l16) * 32 + quad * 8];
#pragma unroll
            for (int j = 0; j < 4; ++j)
                bfv[j] = *(const bf16x8*)&Bs[h][(wn * 64 + j * 16 + l16) * 32 + quad * 8];

#pragma unroll
            for (int i = 0; i < 4; ++i)
#pragma unroll
                for (int j = 0; j < 4; ++j)
                    acc[i][j] = __builtin_amdgcn_mfma_f32_16x16x32_bf16(af[i], bfv[j], acc[i][j], 0, 0, 0);
        }
    }

    // epilogue: store x as bf16 + accumulate stats in fp32
    float psum[4] = {0,0,0,0}, pssq[4] = {0,0,0,0};
#pragma unroll
    for (int i = 0; i < 4; ++i)
#pragma unroll
        for (int j = 0; j < 4; ++j)
#pragma unroll
            for (int r = 0; r < 4; ++r) {
                float v = acc[i][j][r];
                int rr = row0 + wm * 64 + i * 16 + quad * 4 + r;
                int cc = col0 + wn * 64 + j * 16 + l16;
                Xb[(size_t)rr * N + cc] = (__bf16)v;
                psum[j] += v;
                pssq[j] += v * v;
            }
    stats_reduce_store(psum, pssq, scale_o, shift_o, gamma, beta, sred,
                       row0, col0, N, wm, wn, l16, quad, tid);
}

// ---------------------------------------------------------------------------
// Fallback GEMM (ws too small): fp32 inputs, in-kernel convert, fp32 x out
// ---------------------------------------------------------------------------
#define LDSS 40
__global__ __launch_bounds__(256) void gemm_f32_kernel(
    const float* __restrict__ A, const float* __restrict__ W,
    float* __restrict__ C, float* __restrict__ scale_o, float* __restrict__ shift_o,
    const float* __restrict__ gamma, const float* __restrict__ beta,
    int M, int N, int K)
{
    __shared__ __align__(16) __bf16 As[TILE_M * LDSS];
    __shared__ __align__(16) __bf16 Bs[TILE_N * LDSS];
    __shared__ float sred[2][2][128];

    const int tid  = threadIdx.x;
    const int lane = tid & 63;
    const int wave = tid >> 6;
    const int wm   = wave >> 1;
    const int wn   = wave & 1;
    const int quad = lane >> 4;
    const int l16  = lane & 15;

    const int row0 = blockIdx.y * TILE_M;
    const int col0 = blockIdx.x * TILE_N;

    f32x4 acc[4][4];
#pragma unroll
    for (int i = 0; i < 4; ++i)
#pragma unroll
        for (int j = 0; j < 4; ++j) {
            f32x4 z = {0.f, 0.f, 0.f, 0.f};
            acc[i][j] = z;
        }

    for (int k0 = 0; k0 < K; k0 += 32) {
        __syncthreads();
#pragma unroll
        for (int i = 0; i < 4; ++i) {
            int chunk = tid + i * 256;
            int r  = chunk >> 3;
            int c4 = chunk & 7;
            float4 av = *(const float4*)&A[(size_t)(row0 + r) * K + k0 + c4 * 4];
            float4 bv = *(const float4*)&W[(size_t)(col0 + r) * K + k0 + c4 * 4];
            bf16x4 a16 = { (__bf16)av.x, (__bf16)av.y, (__bf16)av.z, (__bf16)av.w };
            bf16x4 b16 = { (__bf16)bv.x, (__bf16)bv.y, (__bf16)bv.z, (__bf16)bv.w };
            *(bf16x4*)&As[r * LDSS + c4 * 4] = a16;
            *(bf16x4*)&Bs[r * LDSS + c4 * 4] = b16;
        }
        __syncthreads();

        bf16x8 af[4], bfv[4];
#pragma unroll
        for (int i = 0; i < 4; ++i)
            af[i]  = *(const bf16x8*)&As[(wm * 64 + i * 16 + l16) * LDSS + quad * 8];
#pragma unroll
        for (int j = 0; j < 4; ++j)
            bfv[j] = *(const bf16x8*)&Bs[(wn * 64 + j * 16 + l16) * LDSS + quad * 8];

#pragma unroll
        for (int i = 0; i < 4; ++i)
#pragma unroll
            for (int j = 0; j < 4; ++j)
                acc[i][j] = __builtin_amdgcn_mfma_f32_16x16x32_bf16(af[i], bfv[j], acc[i][j], 0, 0, 0);
    }

    float psum[4] = {0,0,0,0}, pssq[4] = {0,0,0,0};
#pragma unroll
    for (int i = 0; i < 4; ++i)
#pragma unroll
        for (int j = 0; j < 4; ++j)
#pragma unroll
            for (int r = 0; r < 4; ++r) {
                float v = acc[i][j][r];
                int rr = row0 + wm * 64 + i * 16 + quad * 4 + r;
                int cc = col0 + wn * 64 + j * 16 + l16;
                C[(size_t)rr * N + cc] = v;
                psum[j] += v;
                pssq[j] += v * v;
            }
    stats_reduce_store(psum, pssq, scale_o, shift_o, gamma, beta, sred,
                       row0, col0, N, wm, wn, l16, quad, tid);
}

// ---------------------------------------------------------------------------
// BN-apply * priors -> sparsemax, bf16-x variant. One 256-thr block per row,
// 8 elems/lane; Michelot warm-started at tau0 = zmax-1. Requires N == 2048.
// ---------------------------------------------------------------------------
__device__ __forceinline__ float michelot_tau(
    const float (&z)[8], float mx, float (*red)[4][2], int lane, int wave)
{
    float tau   = mx - 1.0f;
    float kprev = -1.0f;
    for (int it = 0; it < 32; ++it) {
        float s = 0.f, c = 0.f;
#pragma unroll
        for (int i = 0; i < 8; ++i) {
            bool m = z[i] > tau;
            s += m ? z[i] : 0.f;
            c += m ? 1.f  : 0.f;
        }
#pragma unroll
        for (int m = 1; m < 64; m <<= 1) {
            s += __shfl_xor(s, m, 64);
            c += __shfl_xor(c, m, 64);
        }
        if (lane == 0) { red[it & 1][wave][0] = s; red[it & 1][wave][1] = c; }
        __syncthreads();
        s = red[it & 1][0][0] + red[it & 1][1][0] + red[it & 1][2][0] + red[it & 1][3][0];
        c = red[it & 1][0][1] + red[it & 1][1][1] + red[it & 1][2][1] + red[it & 1][3][1];
        float tnew = (s - 1.0f) / c;
        bool done = (c == kprev);     // block-uniform (from reduced values)
        kprev = c;
        tau = tnew;
        if (done) break;              // support unchanged -> tau exact
    }
    return tau;
}

__global__ __launch_bounds__(256) void bn_sparsemax_bf16_kernel(
    const __bf16* __restrict__ xb,
    float* __restrict__ outp,
    const float* __restrict__ priors,
    const float* __restrict__ scale_s,
    const float* __restrict__ shift_s,
    int N)
{
    __shared__ float red[2][4][2];
    __shared__ float mred[4];

    const int tid  = threadIdx.x;
    const int lane = tid & 63;
    const int wave = tid >> 6;
    const int row  = blockIdx.x;
    const int g    = row >> 7;            // VBS = 128
    const size_t base  = (size_t)row * N;
    const size_t gbase = (size_t)g * N;
    const int c0 = tid * 4;
    const int c1 = 1024 + tid * 4;        // order-invariant split

    bf16x4 xh0 = *(const bf16x4*)&xb[base + c0];
    bf16x4 xh1 = *(const bf16x4*)&xb[base + c1];
    float4 p0 = *(const float4*)&priors[base + c0];
    float4 p1 = *(const float4*)&priors[base + c1];
    float4 a0 = *(const float4*)&scale_s[gbase + c0];
    float4 a1 = *(const float4*)&scale_s[gbase + c1];
    float4 b0 = *(const float4*)&shift_s[gbase + c0];
    float4 b1 = *(const float4*)&shift_s[gbase + c1];

    float z[8];
    z[0] = fmaf((float)xh0[0], a0.x, b0.x) * p0.x;
    z[1] = fmaf((float)xh0[1], a0.y, b0.y) * p0.y;
    z[2] = fmaf((float)xh0[2], a0.z, b0.z) * p0.z;
    z[3] = fmaf((float)xh0[3], a0.w, b0.w) * p0.w;
    z[4] = fmaf((float)xh1[0], a1.x, b1.x) * p1.x;
    z[5] = fmaf((float)xh1[1], a1.y, b1.y) * p1.y;
    z[6] = fmaf((float)xh1[2], a1.z, b1.z) * p1.z;
    z[7] = fmaf((float)xh1[3], a1.w, b1.w) * p1.w;

    float mx = z[0];
#pragma unroll
    for (int i = 1; i < 8; ++i) mx = fmaxf(mx, z[i]);
#pragma unroll
    for (int m = 1; m < 64; m <<= 1) mx = fmaxf(mx, __shfl_xor(mx, m, 64));
    if (lane == 0) mred[wave] = mx;
    __syncthreads();
    mx = fmaxf(fmaxf(mred[0], mred[1]), fmaxf(mred[2], mred[3]));

    float tau = michelot_tau(z, mx, red, lane, wave);

    float4 o0, o1;
    o0.x = fmaxf(z[0] - tau, 0.f);
    o0.y = fmaxf(z[1] - tau, 0.f);
    o0.z = fmaxf(z[2] - tau, 0.f);
    o0.w = fmaxf(z[3] - tau, 0.f);
    o1.x = fmaxf(z[4] - tau, 0.f);
    o1.y = fmaxf(z[5] - tau, 0.f);
    o1.z = fmaxf(z[6] - tau, 0.f);
    o1.w = fmaxf(z[7] - tau, 0.f);
    *(float4*)&outp[base + c0] = o0;
    *(float4*)&outp[base + c1] = o1;
}

// fp32-x variant (fallback path; in-place on d_out)
__global__ __launch_bounds__(256) void bn_sparsemax_f32_kernel(
    float* __restrict__ x,
    const float* __restrict__ priors,
    const float* __restrict__ scale_s,
    const float* __restrict__ shift_s,
    int N)
{
    __shared__ float red[2][4][2];
    __shared__ float mred[4];

    const int tid  = threadIdx.x;
    const int lane = tid & 63;
    const int wave = tid >> 6;
    const int row  = blockIdx.x;
    const int g    = row >> 7;
    const size_t base  = (size_t)row * N;
    const size_t gbase = (size_t)g * N;
    const int c0 = tid * 4;
    const int c1 = 1024 + tid * 4;

    float4 x0 = *(const float4*)&x[base + c0];
    float4 x1 = *(const float4*)&x[base + c1];
    float4 p0 = *(const float4*)&priors[base + c0];
    float4 p1 = *(const float4*)&priors[base + c1];
    float4 a0 = *(const float4*)&scale_s[gbase + c0];
    float4 a1 = *(const float4*)&scale_s[gbase + c1];
    float4 b0 = *(const float4*)&shift_s[gbase + c0];
    float4 b1 = *(const float4*)&shift_s[gbase + c1];

    float z[8];
    z[0] = fmaf(x0.x, a0.x, b0.x) * p0.x;
    z[1] = fmaf(x0.y, a0.y, b0.y) * p0.y;
    z[2] = fmaf(x0.z, a0.z, b0.z) * p0.z;
    z[3] = fmaf(x0.w, a0.w, b0.w) * p0.w;
    z[4] = fmaf(x1.x, a1.x, b1.x) * p1.x;
    z[5] = fmaf(x1.y, a1.y, b1.y) * p1.y;
    z[6] = fmaf(x1.z, a1.z, b1.z) * p1.z;
    z[7] = fmaf(x1.w, a1.w, b1.w) * p1.w;

    float mx = z[0];
#pragma unroll
    for (int i = 1; i < 8; ++i) mx = fmaxf(mx, z[i]);
#pragma unroll
    for (int m = 1; m < 64; m <<= 1) mx = fmaxf(mx, __shfl_xor(mx, m, 64));
    if (lane == 0) mred[wave] = mx;
    __syncthreads();
    mx = fmaxf(fmaxf(mred[0], mred[1]), fmaxf(mred[2], mred[3]));

    float tau = michelot_tau(z, mx, red, lane, wave);

    float4 o0, o1;
    o0.x = fmaxf(z[0] - tau, 0.f);
    o0.y = fmaxf(z[1] - tau, 0.f);
    o0.z = fmaxf(z[2] - tau, 0.f);
    o0.w = fmaxf(z[3] - tau, 0.f);
    o1.x = fmaxf(z[4] - tau, 0.f);
    o1.y = fmaxf(z[5] - tau, 0.f);
    o1.z = fmaxf(z[6] - tau, 0.f);
    o1.w = fmaxf(z[7] - tau, 0.f);
    *(float4*)&x[base + c0] = o0;
    *(float4*)&x[base + c1] = o1;
}

// ---------------------------------------------------------------------------
extern "C" void kernel_launch(void* const* d_in, const int* in_sizes, int n_in,
                              void* d_out, int out_size, void* d_ws, size_t ws_size,
                              hipStream_t stream)
{
    const float* priors = (const float*)d_in[0];
    const float* feat   = (const float*)d_in[1];
    const float* fc_w   = (const float*)d_in[2];
    const float* gamma  = (const float*)d_in[3];
    const float* beta   = (const float*)d_in[4];
    float* out = (float*)d_out;

    const int G = in_sizes[3];               // 2048
    const int K = in_sizes[2] / G;           // 2048
    const int B = in_sizes[1] / K;           // 16384
    const int nGroups = B / 128;             // 128

    const size_t statsElems = (size_t)nGroups * G;
    float* scale_s = (float*)d_ws;
    float* shift_s = scale_s + statsElems;
    char* wsAfterStats = (char*)(shift_s + statsElems);

    const size_t nFeat = (size_t)B * K;
    const size_t nW    = (size_t)G * K;
    const size_t nX    = (size_t)B * G;
    const size_t statsBytes = 2 * statsElems * sizeof(float);
    const size_t needBf16   = statsBytes + (nFeat + nW) * sizeof(__bf16);
    const size_t needXb     = needBf16 + nX * sizeof(__bf16);

    if (ws_size >= needXb) {
        // fast path: bf16 operands + bf16 x hand-off
        __bf16* featb = (__bf16*)wsAfterStats;
        __bf16* wb    = featb + nFeat;
        __bf16* xb    = wb + nW;
        long totalChunks = (long)((nFeat + nW) / 8);
        convert_kernel<<<(totalChunks + 255) / 256, 256, 0, stream>>>(
            feat, fc_w, featb, wb, (long)nFeat, (long)nW);
        gemm_bf16_kernel<<<dim3(G / TILE_N, B / TILE_M), 256, 0, stream>>>(
            featb, wb, xb, scale_s, shift_s, gamma, beta, B, G, K);
        bn_sparsemax_bf16_kernel<<<B, 256, 0, stream>>>(
            xb, out, priors, scale_s, shift_s, G);
    } else if (ws_size >= needBf16) {
        // bf16 operands, fp32 x via d_out (round-5 behavior, BK=32 fallback
        // uses the f32 kernel's structure only when even operands don't fit)
        __bf16* featb = (__bf16*)wsAfterStats;
        __bf16* wb    = featb + nFeat;
        long totalChunks = (long)((nFeat + nW) / 8);
        convert_kernel<<<(totalChunks + 255) / 256, 256, 0, stream>>>(
            feat, fc_w, featb, wb, (long)nFeat, (long)nW);
        // reuse f32 bn path with fp32 x in d_out: gemm writes fp32 via
        // gemm_f32-style epilogue is not available for bf16 inputs, so write
        // bf16 x is impossible here; fall back to fp32 gemm on raw inputs.
        gemm_f32_kernel<<<dim3(G / TILE_N, B / TILE_M), 256, 0, stream>>>(
            feat, fc_w, out, scale_s, shift_s, gamma, beta, B, G, K);
        bn_sparsemax_f32_kernel<<<B, 256, 0, stream>>>(
            out, priors, scale_s, shift_s, G);
    } else {
        gemm_f32_kernel<<<dim3(G / TILE_N, B / TILE_M), 256, 0, stream>>>(
            feat, fc_w, out, scale_s, shift_s, gamma, beta, B, G, K);
        bn_sparsemax_f32_kernel<<<B, 256, 0, stream>>>(
            out, priors, scale_s, shift_s, G);
    }
}